// Round 2
// baseline (400.660 us; speedup 1.0000x reference)
//
#include <hip/hip_runtime.h>
#include <hip/hip_bf16.h>
#include <hip/hip_cooperative_groups.h>
#include <math.h>

namespace cg = cooperative_groups;

// B=8, T=2048, C=1024, H=64 causal single-head attention, scale 1/32.
// Single cooperative kernel, 256 blocks x 512 thr (1 block/CU), 4 phases:
//   0: Wt2 (W -> MFMA B-frag order)           [blocks 0..47]
//   1: QKV 64-row tiles, 3-deep B pipeline via global_load_lds, vmcnt(5)
//   2: split-K flash attention, 4608 wave-units over 2048 waves
//   3: combine partials
// grid.sync() between phases replaces 3 kernel-launch gaps.

#define BT 16384
#define TSEQ 2048
#define XST 72   // LDS row stride (ushorts)

typedef __attribute__((ext_vector_type(8))) __bf16 bf16x8;
typedef __attribute__((ext_vector_type(8))) unsigned short ushort8;
typedef __attribute__((ext_vector_type(4))) float floatx4;

#define MFMA16(a, b, c) __builtin_amdgcn_mfma_f32_16x16x32_bf16( \
    __builtin_bit_cast(bf16x8, (a)), __builtin_bit_cast(bf16x8, (b)), (c), 0, 0, 0)

__device__ inline unsigned short f2bf(float f) {
  unsigned u = __builtin_bit_cast(unsigned, f);
  u += 0x7FFFu + ((u >> 16) & 1u);   // RNE
  return (unsigned short)(u >> 16);
}
__device__ inline float bf2f(unsigned short s) {
  return __builtin_bit_cast(float, (unsigned)s << 16);
}
__device__ inline unsigned long long pack4bf(floatx4 f) {
  return (unsigned long long)f2bf(f[0]) | ((unsigned long long)f2bf(f[1]) << 16) |
         ((unsigned long long)f2bf(f[2]) << 32) | ((unsigned long long)f2bf(f[3]) << 48);
}
__device__ inline ushort8 pack8bf(floatx4 a, floatx4 b) {
  ushort8 t;
#pragma unroll
  for (int i = 0; i < 4; ++i) t[i] = f2bf(a[i]);
#pragma unroll
  for (int i = 0; i < 4; ++i) t[4 + i] = f2bf(b[i]);
  return t;
}
__device__ inline void glds16(const unsigned short* g, unsigned short* l) {
  __builtin_amdgcn_global_load_lds(
      (const __attribute__((address_space(1))) unsigned int*)g,
      (__attribute__((address_space(3))) unsigned int*)l, 16, 0, 0);
}

// phase-1 LDS layout (u16 units):
#define XBS 4608     // one x buffer: [64][72]
#define BB0 9216     // B region base (= 2*XBS)
#define BBS 12288    // one B buffer: 24 frags x 512
// total = BB0 + 3*BBS = 46080 u16 = 92160 B  (1 block/CU)

__global__ __launch_bounds__(512, 2) void fused_attn(
    const float* __restrict__ x, const float* __restrict__ Wq,
    const float* __restrict__ Wk, const float* __restrict__ Wv,
    unsigned short* __restrict__ Wt2, unsigned short* __restrict__ Qf,
    unsigned short* __restrict__ Kf, unsigned short* __restrict__ Vf,
    float* __restrict__ part, float* __restrict__ out) {
  __shared__ __align__(16) unsigned short smem[46080];
  const int tid = threadIdx.x;
  const int w = tid >> 6, lane = tid & 63;
  const int quad = lane >> 4, l16 = lane & 15;
  cg::grid_group grid = cg::this_grid();

  // ============================ phase 0: Wt2 ============================
  // flat u16 = ((nt*16 + kci)*2 + half)*512 + lane*8 ; elem j = W[c][h],
  // c = kci*64 + half*32 + quad*8 + j, h = (nt&3)*16 + l16, mat = nt>>2.
  if (blockIdx.x < 48) {
    float* ls = (float*)smem;   // [64][65]
    const int m = blockIdx.x >> 4, kci = blockIdx.x & 15, c0 = kci << 6;
    const float* __restrict__ W = (m == 0) ? Wq : (m == 1) ? Wk : Wv;
#pragma unroll
    for (int i = 0; i < 8; ++i) {
      int idx = tid + (i << 9);
      int cl = idx >> 6, h = idx & 63;
      ls[cl * 65 + h] = W[(c0 + cl) * 64 + h];
    }
    __syncthreads();
    if (tid < 256) {                       // w in 0..3 here
      const int nt = (m << 2) + w;
#pragma unroll
      for (int half = 0; half < 2; ++half) {
        ushort8 t;
#pragma unroll
        for (int j = 0; j < 8; ++j)
          t[j] = f2bf(ls[((half << 5) + (quad << 3) + j) * 65 + (w << 4) + l16]);
        *(ushort8*)(Wt2 + ((size_t)(((nt << 4) + kci) * 2 + half) << 9) +
                    (lane << 3)) = t;
      }
    }
  }
  __threadfence();
  grid.sync();

  // ============================ phase 1: QKV ============================
  // Wave (wr,wn): rows wr*32..+31, nt {3wn..3wn+2}. 3-deep B pipeline:
  // iter c issues x(c+2) then B(c+2); barrier waits vmcnt(5) = drain B(c+1)
  // (issued one full chunk earlier -> latency hidden). ds_write of x(c+1)
  // waits only the (older) x loads, keeping B in flight.
  {
    const int wr = w >> 2, wn = w & 3;
    const int r0 = blockIdx.x << 6;
    const int xrow = (w << 3) + (lane >> 3);
    const int xcol = (lane & 7) << 3;
    const float* __restrict__ xp = x + (size_t)(r0 + xrow) * 1024 + xcol;
    const int xw_u16 = xrow * XST + xcol;

    floatx4 acc[2][3];
#pragma unroll
    for (int rt = 0; rt < 2; ++rt)
#pragma unroll
      for (int n = 0; n < 3; ++n) acc[rt][n] = (floatx4){0.f, 0.f, 0.f, 0.f};

    floatx4 pf[2][2];
    // prologue issue order (pinned): x(0), B(0), x(1), B(1)
    pf[0][0] = *(const floatx4*)(xp);
    pf[0][1] = *(const floatx4*)(xp + 4);
    __builtin_amdgcn_sched_barrier(0);
#pragma unroll
    for (int i = 0; i < 3; ++i) {
      const int f = 3 * w + i;
      glds16(Wt2 + ((size_t)(((f >> 1) << 4) * 2 + (f & 1)) << 9) + (lane << 3),
             &smem[BB0 + (f << 9)]);
    }
    __builtin_amdgcn_sched_barrier(0);
    pf[1][0] = *(const floatx4*)(xp + 64);
    pf[1][1] = *(const floatx4*)(xp + 68);
    __builtin_amdgcn_sched_barrier(0);
#pragma unroll
    for (int i = 0; i < 3; ++i) {
      const int f = 3 * w + i;
      glds16(Wt2 + ((size_t)((((f >> 1) << 4) + 1) * 2 + (f & 1)) << 9) +
                 (lane << 3),
             &smem[BB0 + BBS + (f << 9)]);
    }
    __builtin_amdgcn_sched_barrier(0);
    *(ushort8*)&smem[xw_u16] = pack8bf(pf[0][0], pf[0][1]);  // waits x(0) only
    __builtin_amdgcn_sched_barrier(0);
    asm volatile("s_waitcnt vmcnt(5)");    // B(0) done; x(1),B(1) flying
    asm volatile("s_waitcnt lgkmcnt(0)");
    __builtin_amdgcn_sched_barrier(0);
    __builtin_amdgcn_s_barrier();
    __builtin_amdgcn_sched_barrier(0);

#pragma unroll
    for (int c = 0; c < 16; ++c) {
      // stage xb[(c+1)&1] <- x(c+1) regs (compiler waits the older x loads)
      if (c + 1 < 16)
        *(ushort8*)&smem[((c + 1) & 1) * XBS + xw_u16] =
            pack8bf(pf[(c + 1) & 1][0], pf[(c + 1) & 1][1]);
      __builtin_amdgcn_sched_barrier(0);
      if (c + 2 < 16) {
        pf[c & 1][0] = *(const floatx4*)(xp + ((c + 2) << 6));
        pf[c & 1][1] = *(const floatx4*)(xp + ((c + 2) << 6) + 4);
        __builtin_amdgcn_sched_barrier(0);
#pragma unroll
        for (int i = 0; i < 3; ++i) {
          const int f = 3 * w + i;
          glds16(Wt2 + ((size_t)((((f >> 1) << 4) + (c + 2)) * 2 + (f & 1)) << 9) +
                     (lane << 3),
                 &smem[BB0 + ((c + 2) % 3) * BBS + (f << 9)]);
        }
      }
      __builtin_amdgcn_sched_barrier(0);

      // ---- compute chunk c from xb[c&1], Bb[c%3] ----
      ushort8 af[2][2];
#pragma unroll
      for (int rt = 0; rt < 2; ++rt)
#pragma unroll
        for (int h = 0; h < 2; ++h)
          af[rt][h] = *(const ushort8*)&smem[(c & 1) * XBS +
              ((wr << 5) + (rt << 4) + l16) * XST + (h << 5) + (quad << 3)];
      ushort8 bfr[3][2];
#pragma unroll
      for (int n = 0; n < 3; ++n)
#pragma unroll
        for (int h = 0; h < 2; ++h)
          bfr[n][h] = *(const ushort8*)&smem[BB0 + (c % 3) * BBS +
              ((((3 * wn + n) << 1) + h) << 9) + (lane << 3)];
#pragma unroll
      for (int h = 0; h < 2; ++h)
#pragma unroll
        for (int rt = 0; rt < 2; ++rt)
#pragma unroll
          for (int n = 0; n < 3; ++n)
            acc[rt][n] = MFMA16(af[rt][h], bfr[n][h], acc[rt][n]);

      __builtin_amdgcn_sched_barrier(0);
      if (c < 14) { asm volatile("s_waitcnt vmcnt(5)"); }  // drain B(c+1) only
      else        { asm volatile("s_waitcnt vmcnt(0)"); }
      asm volatile("s_waitcnt lgkmcnt(0)");
      __builtin_amdgcn_sched_barrier(0);
      __builtin_amdgcn_s_barrier();
      __builtin_amdgcn_sched_barrier(0);
    }

    // ---- epilogue: stage Q/K row-major, V transposed (reuse loop LDS) ----
#pragma unroll
    for (int n = 0; n < 3; ++n) {
      const int nt = 3 * wn + n;
      const int m = nt >> 2, hg = nt & 3;
#pragma unroll
      for (int rt = 0; rt < 2; ++rt) {
        const int rowb = (wr << 5) + (rt << 4) + (quad << 2);
        if (m < 2) {
#pragma unroll
          for (int r = 0; r < 4; ++r)
            smem[m * XBS + (rowb + r) * XST + (hg << 4) + l16] =
                f2bf(acc[rt][n][r]);
        } else {
          *(unsigned long long*)&smem[2 * XBS + ((hg << 4) + l16) * XST + rowb] =
              pack4bf(acc[rt][n]);
        }
      }
    }
    __syncthreads();

    // ---- emit fragment-packed Qf/Kf/Vf: 24 frags, 3 per wave, 1KB each ----
    const int bb = blockIdx.x >> 5, st = blockIdx.x & 31;
#pragma unroll
    for (int i = 0; i < 3; ++i) {
      const int f = w * 3 + i;
      const int m = f >> 3, idx = f & 7, grp = idx >> 1, kh = idx & 1;
      ushort8 t = *(const ushort8*)&smem[m * XBS + ((grp << 4) + l16) * XST +
                                         (kh << 5) + (quad << 3)];
      unsigned short* dst;
      if (m == 0)
        dst = Qf + (((size_t)(bb * 128 + (st << 2) + grp) * 2 + kh) << 9);
      else if (m == 1)
        dst = Kf + (((size_t)((bb * 32 + st) * 4 + grp) * 2 + kh) << 9);
      else
        dst = Vf + (((size_t)((bb * 32 + st) * 4 + grp) * 2 + kh) << 9);
      *(ushort8*)(dst + (lane << 3)) = t;
    }
  }
  __threadfence();
  grid.sync();

  // ======================= phase 2: flash attention =====================
  // 4608 wave-units (b<8, e<144, rg<4) over 2048 resident waves.
  {
    unsigned short* Pww = &smem[w * 1152];   // wave-private [16][72]
    const ushort8 ones = {0x3F80, 0x3F80, 0x3F80, 0x3F80,
                          0x3F80, 0x3F80, 0x3F80, 0x3F80};
    for (int u = (blockIdx.x << 3) + w; u < 4608; u += 2048) {
      const int b = u / 576;
      const int ru = u - b * 576;
      const int e = ru >> 2;
      const int rg = ru & 3;
      int g = 0;
#pragma unroll
      for (int gg = 1; gg < 8; ++gg) g += (e >= 2 * gg * (gg + 1)) ? 1 : 0;
      const int rem2 = e - 2 * g * (g + 1);
      const int qt = (g << 2) + rem2 / (g + 1);
      const int ch = rem2 - (rem2 / (g + 1)) * (g + 1);
      const int s0 = ch << 2;
      const int s1 = (s0 + 4 < qt + 1) ? s0 + 4 : qt + 1;
      const int r16 = (qt << 2) + rg;

      const unsigned short* qbase =
          Qf + ((((size_t)b * 128 + r16) * 2) << 9) + (lane << 3);
      ushort8 qf0 = *(const ushort8*)qbase;
      ushort8 qf1 = *(const ushort8*)(qbase + 512);

      floatx4 acc[4], lacc;
#pragma unroll
      for (int nt = 0; nt < 4; ++nt) acc[nt] = (floatx4){0.f, 0.f, 0.f, 0.f};
      lacc = (floatx4){0.f, 0.f, 0.f, 0.f};

#define KVIDX(ss, nt, kh) \
  (((((size_t)(b * 32 + (ss)) << 2) + (nt)) * 2 + (kh)) << 9)

      ushort8 bk[4][2];
#pragma unroll
      for (int nt = 0; nt < 4; ++nt)
#pragma unroll
        for (int kh = 0; kh < 2; ++kh)
          bk[nt][kh] = *(const ushort8*)(Kf + KVIDX(s0, nt, kh) + (lane << 3));

      for (int s = s0; s < s1; ++s) {
        const int sn = (s + 1 < s1) ? s + 1 : s;
        ushort8 bv[4][2];
#pragma unroll
        for (int nt = 0; nt < 4; ++nt)
#pragma unroll
          for (int kh = 0; kh < 2; ++kh)
            bv[nt][kh] = *(const ushort8*)(Vf + KVIDX(s, nt, kh) + (lane << 3));
        ushort8 bkn[4][2];
#pragma unroll
        for (int nt = 0; nt < 4; ++nt)
#pragma unroll
          for (int kh = 0; kh < 2; ++kh)
            bkn[nt][kh] = *(const ushort8*)(Kf + KVIDX(sn, nt, kh) + (lane << 3));

        // S = Q K^T
        floatx4 sf[4];
#pragma unroll
        for (int nt = 0; nt < 4; ++nt) {
          sf[nt] = (floatx4){0.f, 0.f, 0.f, 0.f};
          sf[nt] = MFMA16(qf0, bk[nt][0], sf[nt]);
          sf[nt] = MFMA16(qf1, bk[nt][1], sf[nt]);
        }

        // P = exp(S/32) (no max-shift), causal mask on diagonal tile
        const bool diag = (s == qt);
        const int qrow = (rg << 4) + (quad << 2);
#pragma unroll
        for (int nt = 0; nt < 4; ++nt) {
          const int keyl = (nt << 4) + l16;
#pragma unroll
          for (int r = 0; r < 4; ++r) {
            float ev = __expf(sf[nt][r] * 0.03125f);
            if (diag && keyl > qrow + r) ev = 0.f;
            Pww[((quad << 2) + r) * XST + keyl] = f2bf(ev);
          }
        }

        // O += P V ; l += P 1   (same-wave LDS round trip)
#pragma unroll
        for (int kh = 0; kh < 2; ++kh) {
          ushort8 pa = *(const ushort8*)&Pww[l16 * XST + (kh << 5) + (quad << 3)];
          lacc = MFMA16(pa, ones, lacc);
#pragma unroll
          for (int nt = 0; nt < 4; ++nt) acc[nt] = MFMA16(pa, bv[nt][kh], acc[nt]);
        }
#pragma unroll
        for (int nt = 0; nt < 4; ++nt) {
          bk[nt][0] = bkn[nt][0];
          bk[nt][1] = bkn[nt][1];
        }
      }
#undef KVIDX

      float* slot = part + (size_t)(b * 144 + e) * 2112;
      if (l16 == 0) {
#pragma unroll
        for (int r = 0; r < 4; ++r) slot[(rg << 4) + (quad << 2) + r] = lacc[r];
      }
      unsigned short* op = (unsigned short*)(slot + 64);
#pragma unroll
      for (int nt = 0; nt < 4; ++nt)
#pragma unroll
        for (int r = 0; r < 4; ++r)
          op[((rg << 4) + (quad << 2) + r) * 64 + (nt << 4) + l16] =
              f2bf(acc[nt][r]);
    }
  }
  __threadfence();
  grid.sync();

  // ========================== phase 3: combine ==========================
  {
    const int ob = (blockIdx.x << 1) | (tid >> 8);   // orig block 0..511
    const int t = tid & 255;
    const int rh = ob & 1;
    const int bqt = ob >> 1;
    const int b = bqt >> 5, qt = bqt & 31;
    const int row = (rh << 5) + (t >> 3);
    const int hseg = (t & 7) << 3;
    const int g = qt >> 2;
    const int nch = g + 1;
    const int ebase = 2 * g * (g + 1) + (qt & 3) * (g + 1);

    float l = 0.f;
    float ov[8];
#pragma unroll
    for (int i = 0; i < 8; ++i) ov[i] = 0.f;
    for (int c = 0; c < nch; ++c) {
      const float* slot = part + (size_t)(b * 144 + ebase + c) * 2112;
      l += slot[row];
      ushort8 o0 = *(const ushort8*)((const unsigned short*)(slot + 64) +
                                     row * 64 + hseg);
#pragma unroll
      for (int i = 0; i < 8; ++i) ov[i] += bf2f(o0[i]);
    }
    const float inv = 1.f / l;
    float* o = out + ((size_t)(b * TSEQ + (qt << 6) + row)) * 64 + hseg;
#pragma unroll
    for (int i = 0; i < 8; ++i) o[i] = ov[i] * inv;
  }
}

extern "C" void kernel_launch(void* const* d_in, const int* in_sizes, int n_in,
                              void* d_out, int out_size, void* d_ws, size_t ws_size,
                              hipStream_t stream) {
  const float* x  = (const float*)d_in[0];
  const float* Wk = (const float*)d_in[1];
  const float* Wq = (const float*)d_in[2];
  const float* Wv = (const float*)d_in[3];

  unsigned short* Qfw = (unsigned short*)d_ws;          // 2 MB
  unsigned short* Kfw = Qfw + (size_t)BT * 64;          // 2 MB
  unsigned short* Vfw = Kfw + (size_t)BT * 64;          // 2 MB
  unsigned short* Wt2 = Vfw + (size_t)BT * 64;          // 384 KB
  float* part = (float*)(Wt2 + 3 * 64 * 1024);          // 1152*8448 B = 9.7 MB
  float* outp = (float*)d_out;

  void* args[] = {(void*)&x,   (void*)&Wq,  (void*)&Wk,  (void*)&Wv,
                  (void*)&Wt2, (void*)&Qfw, (void*)&Kfw, (void*)&Vfw,
                  (void*)&part, (void*)&outp};
  hipLaunchCooperativeKernel((void*)fused_attn, dim3(256), dim3(512), args, 0,
                             stream);
}

// Round 3
// 130.694 us; speedup vs baseline: 3.0656x; 3.0656x over previous
//
#include <hip/hip_runtime.h>
#include <hip/hip_bf16.h>
#include <math.h>

// B=8, T=2048, C=1024, H=64 causal single-head attention, scale 1/32.
// wt2 (W -> B-frag order) -> qkv (64-row blocks, nt-split waves, B via
// global_load_lds 3-deep dbuf + counted vmcnt) -> attn_part (4-wave blocks,
// K/V staged once per block in LDS via global_load_lds dbuf, counted vmcnt)
// -> attn_combine.

#define BT 16384
#define TSEQ 2048
#define XST 72   // LDS row stride (ushorts)

typedef __attribute__((ext_vector_type(8))) __bf16 bf16x8;
typedef __attribute__((ext_vector_type(8))) unsigned short ushort8;
typedef __attribute__((ext_vector_type(4))) float floatx4;

#define MFMA16(a, b, c) __builtin_amdgcn_mfma_f32_16x16x32_bf16( \
    __builtin_bit_cast(bf16x8, (a)), __builtin_bit_cast(bf16x8, (b)), (c), 0, 0, 0)

__device__ inline unsigned short f2bf(float f) {
  unsigned u = __builtin_bit_cast(unsigned, f);
  u += 0x7FFFu + ((u >> 16) & 1u);   // RNE
  return (unsigned short)(u >> 16);
}
__device__ inline float bf2f(unsigned short s) {
  return __builtin_bit_cast(float, (unsigned)s << 16);
}
__device__ inline unsigned long long pack4bf(floatx4 f) {
  return (unsigned long long)f2bf(f[0]) | ((unsigned long long)f2bf(f[1]) << 16) |
         ((unsigned long long)f2bf(f[2]) << 32) | ((unsigned long long)f2bf(f[3]) << 48);
}
__device__ inline ushort8 pack8bf(floatx4 a, floatx4 b) {
  ushort8 t;
#pragma unroll
  for (int i = 0; i < 4; ++i) t[i] = f2bf(a[i]);
#pragma unroll
  for (int i = 0; i < 4; ++i) t[4 + i] = f2bf(b[i]);
  return t;
}
__device__ inline void glds16(const unsigned short* g, unsigned short* l) {
  __builtin_amdgcn_global_load_lds(
      (const __attribute__((address_space(1))) unsigned int*)g,
      (__attribute__((address_space(3))) unsigned int*)l, 16, 0, 0);
}

// ---------------------------------------------------------------------------
// Kernel 0: Wt2 in MFMA B-fragment order, coalesced both ways via LDS bounce.
// flat u16 = ((nt*16 + kci)*2 + half)*512 + lane*8 ; elem j = W[c][h],
// c = kci*64 + half*32 + quad*8 + j, h = (nt&3)*16 + l16, mat = nt>>2.
// ---------------------------------------------------------------------------
__global__ __launch_bounds__(256) void wt2_kernel(
    const float* __restrict__ Wq, const float* __restrict__ Wk,
    const float* __restrict__ Wv, unsigned short* __restrict__ Wt2) {
  __shared__ float ls[64][65];
  const int m = blockIdx.x >> 4;
  const int kci = blockIdx.x & 15;
  const int c0 = kci << 6;
  const float* __restrict__ W = (m == 0) ? Wq : (m == 1) ? Wk : Wv;
  const int tid = threadIdx.x;
#pragma unroll
  for (int i = 0; i < 16; ++i) {
    int idx = tid + (i << 8);
    int cl = idx >> 6, h = idx & 63;
    ls[cl][h] = W[(c0 + cl) * 64 + h];
  }
  __syncthreads();
  const int w = tid >> 6, lane = tid & 63;
  const int quad = lane >> 4, l16 = lane & 15;
  const int nt = (m << 2) + w;
#pragma unroll
  for (int half = 0; half < 2; ++half) {
    ushort8 t;
#pragma unroll
    for (int j = 0; j < 8; ++j)
      t[j] = f2bf(ls[(half << 5) + (quad << 3) + j][(w << 4) + l16]);
    *(ushort8*)(Wt2 + ((size_t)(((nt << 4) + kci) * 2 + half) << 9) +
                (lane << 3)) = t;
  }
}

// ---------------------------------------------------------------------------
// Kernel 1: 64-row M-tile, grid 256 (1 block/CU), 512 thr = 8 waves.
// Wave (wr,wn): rows wr*32..+31, nt {3wn..3wn+2}. 3-deep B pipeline:
// iter c issues x(c+2) then B(c+2); barrier waits vmcnt(5) = drain B(c+1).
// LDS: xb 2x[64][72] + Bb 3x[24][512] u16 = 92 KB.
// ---------------------------------------------------------------------------
#define XBS 4608     // one x buffer: [64][72]
#define BB0 9216     // B region base (= 2*XBS)
#define BBS 12288    // one B buffer: 24 frags x 512

__global__ __launch_bounds__(512) void qkv_mfma(
    const float* __restrict__ x, const unsigned short* __restrict__ Wt2,
    unsigned short* __restrict__ Qf, unsigned short* __restrict__ Kf,
    unsigned short* __restrict__ Vf) {
  __shared__ __align__(16) unsigned short smem[46080];

  const int tid = threadIdx.x;
  const int w = tid >> 6, lane = tid & 63;
  const int quad = lane >> 4, l16 = lane & 15;
  const int wr = w >> 2, wn = w & 3;
  const int r0 = blockIdx.x << 6;
  const int xrow = (w << 3) + (lane >> 3);
  const int xcol = (lane & 7) << 3;
  const float* __restrict__ xp = x + (size_t)(r0 + xrow) * 1024 + xcol;
  const int xw_u16 = xrow * XST + xcol;

  floatx4 acc[2][3];
#pragma unroll
  for (int rt = 0; rt < 2; ++rt)
#pragma unroll
    for (int n = 0; n < 3; ++n) acc[rt][n] = (floatx4){0.f, 0.f, 0.f, 0.f};

  floatx4 pf[2][2];
  // prologue issue order (pinned): x(0), B(0), x(1), B(1)
  pf[0][0] = *(const floatx4*)(xp);
  pf[0][1] = *(const floatx4*)(xp + 4);
  __builtin_amdgcn_sched_barrier(0);
#pragma unroll
  for (int i = 0; i < 3; ++i) {
    const int f = 3 * w + i;
    glds16(Wt2 + ((size_t)(((f >> 1) << 4) * 2 + (f & 1)) << 9) + (lane << 3),
           &smem[BB0 + (f << 9)]);
  }
  __builtin_amdgcn_sched_barrier(0);
  pf[1][0] = *(const floatx4*)(xp + 64);
  pf[1][1] = *(const floatx4*)(xp + 68);
  __builtin_amdgcn_sched_barrier(0);
#pragma unroll
  for (int i = 0; i < 3; ++i) {
    const int f = 3 * w + i;
    glds16(Wt2 + ((size_t)((((f >> 1) << 4) + 1) * 2 + (f & 1)) << 9) +
               (lane << 3),
           &smem[BB0 + BBS + (f << 9)]);
  }
  __builtin_amdgcn_sched_barrier(0);
  *(ushort8*)&smem[xw_u16] = pack8bf(pf[0][0], pf[0][1]);  // waits x(0) only
  __builtin_amdgcn_sched_barrier(0);
  asm volatile("s_waitcnt vmcnt(5)");    // B(0) done; x(1),B(1) flying
  asm volatile("s_waitcnt lgkmcnt(0)");
  __builtin_amdgcn_sched_barrier(0);
  __builtin_amdgcn_s_barrier();
  __builtin_amdgcn_sched_barrier(0);

#pragma unroll
  for (int c = 0; c < 16; ++c) {
    if (c + 1 < 16)
      *(ushort8*)&smem[((c + 1) & 1) * XBS + xw_u16] =
          pack8bf(pf[(c + 1) & 1][0], pf[(c + 1) & 1][1]);
    __builtin_amdgcn_sched_barrier(0);
    if (c + 2 < 16) {
      pf[c & 1][0] = *(const floatx4*)(xp + ((c + 2) << 6));
      pf[c & 1][1] = *(const floatx4*)(xp + ((c + 2) << 6) + 4);
      __builtin_amdgcn_sched_barrier(0);
#pragma unroll
      for (int i = 0; i < 3; ++i) {
        const int f = 3 * w + i;
        glds16(Wt2 + ((size_t)((((f >> 1) << 4) + (c + 2)) * 2 + (f & 1)) << 9) +
                   (lane << 3),
               &smem[BB0 + ((c + 2) % 3) * BBS + (f << 9)]);
      }
    }
    __builtin_amdgcn_sched_barrier(0);

    // ---- compute chunk c from xb[c&1], Bb[c%3] ----
    ushort8 af[2][2];
#pragma unroll
    for (int rt = 0; rt < 2; ++rt)
#pragma unroll
      for (int h = 0; h < 2; ++h)
        af[rt][h] = *(const ushort8*)&smem[(c & 1) * XBS +
            ((wr << 5) + (rt << 4) + l16) * XST + (h << 5) + (quad << 3)];
    ushort8 bfr[3][2];
#pragma unroll
    for (int n = 0; n < 3; ++n)
#pragma unroll
      for (int h = 0; h < 2; ++h)
        bfr[n][h] = *(const ushort8*)&smem[BB0 + (c % 3) * BBS +
            ((((3 * wn + n) << 1) + h) << 9) + (lane << 3)];
#pragma unroll
    for (int h = 0; h < 2; ++h)
#pragma unroll
      for (int rt = 0; rt < 2; ++rt)
#pragma unroll
        for (int n = 0; n < 3; ++n)
          acc[rt][n] = MFMA16(af[rt][h], bfr[n][h], acc[rt][n]);

    __builtin_amdgcn_sched_barrier(0);
    if (c < 14) { asm volatile("s_waitcnt vmcnt(5)"); }  // drain B(c+1) only
    else        { asm volatile("s_waitcnt vmcnt(0)"); }
    asm volatile("s_waitcnt lgkmcnt(0)");
    __builtin_amdgcn_sched_barrier(0);
    __builtin_amdgcn_s_barrier();
    __builtin_amdgcn_sched_barrier(0);
  }

  // ---- epilogue: stage Q/K row-major, V transposed (reuse loop LDS) ----
#pragma unroll
  for (int n = 0; n < 3; ++n) {
    const int nt = 3 * wn + n;
    const int m = nt >> 2, hg = nt & 3;
#pragma unroll
    for (int rt = 0; rt < 2; ++rt) {
      const int rowb = (wr << 5) + (rt << 4) + (quad << 2);
      if (m < 2) {
#pragma unroll
        for (int r = 0; r < 4; ++r)
          smem[m * XBS + (rowb + r) * XST + (hg << 4) + l16] =
              f2bf(acc[rt][n][r]);
      } else {
        *(unsigned long long*)&smem[2 * XBS + ((hg << 4) + l16) * XST + rowb] =
            pack4bf(acc[rt][n]);
      }
    }
  }
  __syncthreads();

  // ---- emit fragment-packed Qf/Kf/Vf: 24 frags, 3 per wave, 1KB each ----
  const int b = blockIdx.x >> 5, st = blockIdx.x & 31;
#pragma unroll
  for (int i = 0; i < 3; ++i) {
    const int f = w * 3 + i;
    const int m = f >> 3, idx = f & 7, grp = idx >> 1, kh = idx & 1;
    ushort8 t = *(const ushort8*)&smem[m * XBS + ((grp << 4) + l16) * XST +
                                       (kh << 5) + (quad << 3)];
    unsigned short* dst;
    if (m == 0)
      dst = Qf + (((size_t)(b * 128 + (st << 2) + grp) * 2 + kh) << 9);
    else if (m == 1)
      dst = Kf + (((size_t)((b * 32 + st) * 4 + grp) * 2 + kh) << 9);
    else
      dst = Vf + (((size_t)((b * 32 + st) * 4 + grp) * 2 + kh) << 9);
    *(ushort8*)(dst + (lane << 3)) = t;
  }
}

// ---------------------------------------------------------------------------
// Kernel 2 (v4): split-K flash attention, 4-wave blocks sharing K/V via LDS.
// Grid 8 x 144 = 1152 blocks x 256 thr; block owns the full 64-row q-tile of
// one (b,e) unit; wave w = 16-row group. Per s-step: 16 KB K/V staged ONCE
// per block by global_load_lds (dbuf, counted vmcnt(4), 2 raw barriers/step).
// L2 frag traffic /4 vs per-wave loads; staging latency hidden under compute.
// LDS: KV 2x16 KB + P 4x2.25 KB = 41 KB -> 3 blocks/CU (12 waves/CU).
// ---------------------------------------------------------------------------
__global__ __launch_bounds__(256, 3) void attn_part(
    const unsigned short* __restrict__ Qf, const unsigned short* __restrict__ Kf,
    const unsigned short* __restrict__ Vf, float* __restrict__ part) {
  __shared__ __align__(16) unsigned short KV[2][8192];   // 16 frag slots x 1KB
  __shared__ unsigned short Pw[4][16 * XST];

  const int tid = threadIdx.x;
  const int w = tid >> 6, lane = tid & 63;
  const int quad = lane >> 4, l16 = lane & 15;
  const int b = blockIdx.x / 144;
  const int e = blockIdx.x - b * 144;
  int g = 0;
#pragma unroll
  for (int gg = 1; gg < 8; ++gg) g += (e >= 2 * gg * (gg + 1)) ? 1 : 0;
  const int rem2 = e - 2 * g * (g + 1);
  const int qt = (g << 2) + rem2 / (g + 1);
  const int ch = rem2 - (rem2 / (g + 1)) * (g + 1);
  const int s0 = ch << 2;
  const int s1 = (s0 + 4 < qt + 1) ? s0 + 4 : qt + 1;
  const int r16 = (qt << 2) + w;

#define KVIDX(ss, nt, kh) \
  (((((size_t)(b * 32 + (ss)) << 2) + (nt)) * 2 + (kh)) << 9)
// slot f (0..15): f<8 -> K frag (nt=f>>1, kh=f&1); f>=8 -> V frag.
// wave w stages slots {w, 4+w, 8+w, 12+w}: 4 glds/wave/step.
#define STAGE_KV(ss, db)                                                     \
  {                                                                          \
    _Pragma("unroll") for (int r_ = 0; r_ < 4; ++r_) {                       \
      const int f_ = (r_ << 2) + w;                                          \
      const unsigned short* src_ =                                           \
          (f_ < 8) ? Kf + KVIDX(ss, (f_ >> 1), (f_ & 1)) + (lane << 3)       \
                   : Vf + KVIDX(ss, (f_ >> 1) - 4, (f_ & 1)) + (lane << 3);  \
      glds16(src_, &KV[db][f_ << 9]);                                        \
    }                                                                        \
  }

  // Q frags for this wave's 16 rows
  const unsigned short* qbase =
      Qf + ((((size_t)b * 128 + r16) * 2) << 9) + (lane << 3);
  ushort8 qf0 = *(const ushort8*)qbase;
  ushort8 qf1 = *(const ushort8*)(qbase + 512);
  __builtin_amdgcn_sched_barrier(0);

  // prologue: stage s0 -> buf0, s0+1 (clamped) -> buf1
  STAGE_KV(s0, 0);
  __builtin_amdgcn_sched_barrier(0);
  STAGE_KV((s0 + 1 < s1) ? s0 + 1 : s1 - 1, 1);
  __builtin_amdgcn_sched_barrier(0);
  asm volatile("s_waitcnt vmcnt(4)");   // Q + stage(s0) done; stage(s0+1) flying
  __builtin_amdgcn_sched_barrier(0);
  __builtin_amdgcn_s_barrier();
  __builtin_amdgcn_sched_barrier(0);

  floatx4 acc[4], lacc;
#pragma unroll
  for (int nt = 0; nt < 4; ++nt) acc[nt] = (floatx4){0.f, 0.f, 0.f, 0.f};
  lacc = (floatx4){0.f, 0.f, 0.f, 0.f};
  const ushort8 ones = {0x3F80, 0x3F80, 0x3F80, 0x3F80,
                        0x3F80, 0x3F80, 0x3F80, 0x3F80};

  for (int s = s0; s < s1; ++s) {
    const int cur = (s - s0) & 1;
    // 1. all 16 frags -> regs (stride-1 ds_read_b128, conflict-free)
    ushort8 bk[4][2], bv[4][2];
#pragma unroll
    for (int nt = 0; nt < 4; ++nt)
#pragma unroll
      for (int kh = 0; kh < 2; ++kh) {
        bk[nt][kh] = *(const ushort8*)&KV[cur][((((nt << 1) + kh)) << 9) +
                                              (lane << 3)];
        bv[nt][kh] = *(const ushort8*)&KV[cur][(((8 + (nt << 1) + kh)) << 9) +
                                              (lane << 3)];
      }
    asm volatile("s_waitcnt lgkmcnt(0)");
    __builtin_amdgcn_sched_barrier(0);
    __builtin_amdgcn_s_barrier();          // all waves done reading buf[cur]
    __builtin_amdgcn_sched_barrier(0);

    // 2. stage s+2 (clamped; uniform vmcnt bookkeeping) into buf[cur]
    STAGE_KV((s + 2 < s1) ? s + 2 : s1 - 1, cur);
    __builtin_amdgcn_sched_barrier(0);

    // 3. S = Q K^T
    floatx4 sf[4];
#pragma unroll
    for (int nt = 0; nt < 4; ++nt) {
      sf[nt] = (floatx4){0.f, 0.f, 0.f, 0.f};
      sf[nt] = MFMA16(qf0, bk[nt][0], sf[nt]);
      sf[nt] = MFMA16(qf1, bk[nt][1], sf[nt]);
    }

    // 4. P = exp(S/32) (no max-shift), causal mask on diagonal tile
    const bool diag = (s == qt);
    const int qrow = (w << 4) + (quad << 2);
#pragma unroll
    for (int nt = 0; nt < 4; ++nt) {
      const int keyl = (nt << 4) + l16;
#pragma unroll
      for (int r = 0; r < 4; ++r) {
        float ev = __expf(sf[nt][r] * 0.03125f);
        if (diag && keyl > qrow + r) ev = 0.f;
        Pw[w][((quad << 2) + r) * XST + keyl] = f2bf(ev);
      }
    }

    // 5. O += P V ; l += P 1   (same-wave LDS round trip)
#pragma unroll
    for (int kh = 0; kh < 2; ++kh) {
      ushort8 pa = *(const ushort8*)&Pw[w][l16 * XST + (kh << 5) + (quad << 3)];
      lacc = MFMA16(pa, ones, lacc);
#pragma unroll
      for (int nt = 0; nt < 4; ++nt) acc[nt] = MFMA16(pa, bv[nt][kh], acc[nt]);
    }

    // 6. tile s+1 arrived (issued a full step ago); s+2's 4 glds remain
    __builtin_amdgcn_sched_barrier(0);
    asm volatile("s_waitcnt vmcnt(4)");
    __builtin_amdgcn_sched_barrier(0);
    __builtin_amdgcn_s_barrier();
    __builtin_amdgcn_sched_barrier(0);
  }
#undef STAGE_KV
#undef KVIDX

  // partial slot: l[64] f32 + o[64][64] bf16; wave owns rows w*16..w*16+15.
  float* slot = part + (size_t)(b * 144 + e) * 2112;
  if (l16 == 0) {
#pragma unroll
    for (int r = 0; r < 4; ++r) slot[(w << 4) + (quad << 2) + r] = lacc[r];
  }
  unsigned short* op = (unsigned short*)(slot + 64);
#pragma unroll
  for (int nt = 0; nt < 4; ++nt)
#pragma unroll
    for (int r = 0; r < 4; ++r)
      op[((w << 4) + (quad << 2) + r) * 64 + (nt << 4) + l16] = f2bf(acc[nt][r]);
}

// ---------------------------------------------------------------------------
// Kernel 3: combine <=8 partials: out = (sum o_i)/(sum l_i). grid = 512
// (b, qt, row-half), 256 thr, 8 u16 per thread, fully coalesced.
// ---------------------------------------------------------------------------
__global__ __launch_bounds__(256) void attn_combine(
    const float* __restrict__ part, float* __restrict__ out) {
  const int rh = blockIdx.x & 1;
  const int bqt = blockIdx.x >> 1;
  const int b = bqt >> 5, qt = bqt & 31;
  const int tid = threadIdx.x;
  const int row = (rh << 5) + (tid >> 3);
  const int hseg = (tid & 7) << 3;
  const int g = qt >> 2;
  const int nch = g + 1;
  const int ebase = 2 * g * (g + 1) + (qt & 3) * (g + 1);

  float l = 0.f;
  float ov[8];
#pragma unroll
  for (int i = 0; i < 8; ++i) ov[i] = 0.f;
  for (int c = 0; c < nch; ++c) {
    const float* slot = part + (size_t)(b * 144 + ebase + c) * 2112;
    l += slot[row];
    ushort8 o0 = *(const ushort8*)((const unsigned short*)(slot + 64) +
                                   row * 64 + hseg);
#pragma unroll
    for (int i = 0; i < 8; ++i) ov[i] += bf2f(o0[i]);
  }
  const float inv = 1.f / l;
  float* o = out + ((size_t)(b * TSEQ + (qt << 6) + row)) * 64 + hseg;
#pragma unroll
  for (int i = 0; i < 8; ++i) o[i] = ov[i] * inv;
}

extern "C" void kernel_launch(void* const* d_in, const int* in_sizes, int n_in,
                              void* d_out, int out_size, void* d_ws, size_t ws_size,
                              hipStream_t stream) {
  const float* x  = (const float*)d_in[0];
  const float* Wk = (const float*)d_in[1];
  const float* Wq = (const float*)d_in[2];
  const float* Wv = (const float*)d_in[3];

  unsigned short* Qfw = (unsigned short*)d_ws;          // 2 MB
  unsigned short* Kfw = Qfw + (size_t)BT * 64;          // 2 MB
  unsigned short* Vfw = Kfw + (size_t)BT * 64;          // 2 MB
  unsigned short* Wt2 = Vfw + (size_t)BT * 64;          // 384 KB
  float* part = (float*)(Wt2 + 3 * 64 * 1024);          // 1152*8448 B = 9.7 MB

  wt2_kernel<<<48, 256, 0, stream>>>(Wq, Wk, Wv, Wt2);
  qkv_mfma<<<256, 512, 0, stream>>>(x, Wt2, Qfw, Kfw, Vfw);
  attn_part<<<1152, 256, 0, stream>>>(Qfw, Kfw, Vfw, part);
  attn_combine<<<512, 256, 0, stream>>>(part, (float*)d_out);
}